// Round 7
// baseline (761.082 us; speedup 1.0000x reference)
//
#include <hip/hip_runtime.h>
#include <hip/hip_cooperative_groups.h>
#include <math.h>

namespace cg = cooperative_groups;

#define NN 384
#define DD 128
#define HH 128

__device__ __forceinline__ float sigmoidf_(float x) { return 1.f / (1.f + __expf(-x)); }
__device__ __forceinline__ float tanhf_(float x)    { return 1.f - 2.f / (__expf(2.f * x) + 1.f); }

struct Params {
  const float *h1, *h2, *adj1, *dmv, *charge1, *charge2, *veps, *vsig, *delta_uff;
  const float *valid1, *valid2, *nm1, *nm2;
  const float *node_W, *gat_W, *gat_Wb, *gat_A, *gat_gW, *gat_gb;
  const float *pW1, *pb1, *pW2, *pb2, *vdw_coeff, *duff_coeff;
  const float *iW1, *ib1, *iW2, *ib2;
  float *out;
  float *h1gA, *h1gB, *h2g, *hbuf, *hAbuf, *hTbuf, *hATbuf, *att, *p1, *p2q, *ws_int;
};

// 256 blocks (1/CU, zero tail) x 384 threads (6 waves). 12 grid syncs.
// Every phase: coalesced operand on lanes; broadcast operand via uniform
// s_loads or same-address float4 loads; NO LDS in hot loops (round-5 lesson).
__global__ __launch_bounds__(384) void k_mega(Params P) {
  cg::grid_group grid = cg::this_grid();
  const int blk = blockIdx.x;
  const int tid = threadIdx.x;
  const int c = tid & 127;     // column lane 0..127
  const int g = tid >> 7;      // row-group 0..2

  // ================= Phase E: embed (1536 rows, 6/block) + out init ========
  if (blk == 0 && tid < 8) {
    int bb = tid >> 2, cc = tid & 3;
    P.out[tid] = (cc == 2) ? P.duff_coeff[0] * P.duff_coeff[0] * P.delta_uff[bb] : 0.f;
  }
  {
    int rb = blk * 6;
    for (int p = 0; p < 2; ++p) {
      int r = rb + p * 3 + g;
      const float* src; float* dst; int rr;
      if (r < 768) { src = P.h1; dst = P.h1gA; rr = r; }
      else         { src = P.h2; dst = P.h2g;  rr = r - 768; }
      const float* xr = src + rr * 54;
      float acc = 0.f;
#pragma unroll 6
      for (int k = 0; k < 54; ++k) acc += xr[k] * P.node_W[k * DD + c];
      dst[rr * DD + c] = acc;
    }
  }
  grid.sync();

  // ================= GAT layers =============================================
  float* cur = P.h1gA;
  float* nxt = P.h1gB;
  for (int l = 0; l < 3; ++l) {
    const float* W  = P.gat_W  + l * DD * DD;
    const float* Wb = P.gat_Wb + l * DD;
    const float* A  = P.gat_A  + l * DD * DD;
    const float* gW = P.gat_gW + l * 2 * DD;
    const float* gb = P.gat_gb + l;

    // ---- H: h = x@W+Wb, hA = h@A. 3 rows/block (row = blk*3+g). ----
    {
      __shared__ float hs[3][DD];
      int r = blk * 3 + g;
      const float4* xr4 = (const float4*)(cur + r * DD);
      float a0 = 0.f, a1 = 0.f;
#pragma unroll 4
      for (int k4 = 0; k4 < DD / 4; ++k4) {
        float4 xv = xr4[k4];
        int k = k4 * 4;
        a0 += xv.x * W[k * DD + c] + xv.z * W[(k + 2) * DD + c];
        a1 += xv.y * W[(k + 1) * DD + c] + xv.w * W[(k + 3) * DD + c];
      }
      float hv = a0 + a1 + Wb[c];
      P.hbuf[r * DD + c] = hv;
      P.hTbuf[c * 768 + r] = hv;
      hs[g][c] = hv;
      __syncthreads();
      const float4* hs4 = (const float4*)hs[g];
      a0 = 0.f; a1 = 0.f;
#pragma unroll 4
      for (int k4 = 0; k4 < DD / 4; ++k4) {
        float4 xv = hs4[k4];
        int k = k4 * 4;
        a0 += xv.x * A[k * DD + c] + xv.z * A[(k + 2) * DD + c];
        a1 += xv.y * A[(k + 1) * DD + c] + xv.w * A[(k + 3) * DD + c];
      }
      float av = a0 + a1;
      P.hAbuf[r * DD + c] = av;
      P.hATbuf[c * 768 + r] = av;
    }
    grid.sync();

    // ---- Att: 3 softmax columns/block, lane = j (384). hT/hAT coalesced
    //      and shared across the 3 cols; k-rows via uniform s_loads. ----
    {
      __shared__ float red[3][6];
      int b = blk >> 7;
      int k0g = blk * 3;
      int kk0 = k0g - b * NN;
      int j = tid;
      const float* hTb  = P.hTbuf  + b * NN + j;
      const float* hATb = P.hATbuf + b * NN + j;
      const float* h0r = P.hbuf  + (k0g + 0) * DD;
      const float* h1r = P.hbuf  + (k0g + 1) * DD;
      const float* h2r = P.hbuf  + (k0g + 2) * DD;
      const float* a0r = P.hAbuf + (k0g + 0) * DD;
      const float* a1r = P.hAbuf + (k0g + 1) * DD;
      const float* a2r = P.hAbuf + (k0g + 2) * DD;
      float e0 = 0.f, e1 = 0.f, e2 = 0.f;
#pragma unroll 4
      for (int cc = 0; cc < DD; ++cc) {
        float tv = hTb[cc * 768], av = hATb[cc * 768];
        e0 += av * h0r[cc] + tv * a0r[cc];
        e1 += av * h1r[cc] + tv * a1r[cc];
        e2 += av * h2r[cc] + tv * a2r[cc];
      }
      float aj0 = P.adj1[(k0g + 0) * NN + j];  // adj symmetric: [k][j] == [j][k]
      float aj1 = P.adj1[(k0g + 1) * NN + j];
      float aj2 = P.adj1[(k0g + 2) * NN + j];
      float l0 = aj0 > 0.f ? e0 : -3e38f;
      float l1 = aj1 > 0.f ? e1 : -3e38f;
      float l2 = aj2 > 0.f ? e2 : -3e38f;
#pragma unroll
      for (int off = 32; off > 0; off >>= 1) {
        l0 = fmaxf(l0, __shfl_down(l0, off));
        l1 = fmaxf(l1, __shfl_down(l1, off));
        l2 = fmaxf(l2, __shfl_down(l2, off));
      }
      int w = tid >> 6;
      if ((tid & 63) == 0) { red[0][w] = l0; red[1][w] = l1; red[2][w] = l2; }
      __syncthreads();
      float m0 = red[0][0], m1 = red[1][0], m2 = red[2][0];
#pragma unroll
      for (int q = 1; q < 6; ++q) {
        m0 = fmaxf(m0, red[0][q]); m1 = fmaxf(m1, red[1][q]); m2 = fmaxf(m2, red[2][q]);
      }
      float v0 = aj0 > 0.f ? __expf(e0 - m0) : 0.f;
      float v1 = aj1 > 0.f ? __expf(e1 - m1) : 0.f;
      float v2 = aj2 > 0.f ? __expf(e2 - m2) : 0.f;
      float s0 = v0, s1 = v1, s2 = v2;
#pragma unroll
      for (int off = 32; off > 0; off >>= 1) {
        s0 += __shfl_down(s0, off);
        s1 += __shfl_down(s1, off);
        s2 += __shfl_down(s2, off);
      }
      __syncthreads();
      if ((tid & 63) == 0) { red[0][w] = s0; red[1][w] = s1; red[2][w] = s2; }
      __syncthreads();
      float d0 = 0.f, d1 = 0.f, d2 = 0.f;
#pragma unroll
      for (int q = 0; q < 6; ++q) { d0 += red[0][q]; d1 += red[1][q]; d2 += red[2][q]; }
      float* arow = P.att + (b * NN + j) * NN + kk0;
      arow[0] = v0 * aj0 / d0;
      arow[1] = v1 * aj1 / d1;
      arow[2] = v2 * aj2 / d2;
    }
    grid.sync();

    // ---- O: h' = relu(att@h); gated residual. 3 rows/block (row=blk*3+g).
    //      att row via same-address float4; h coalesced over c. ----
    {
      __shared__ float redw[3][2];
      int r = blk * 3 + g;
      int b = blk >> 7;
      const float4* ar4 = (const float4*)(P.att + r * NN);
      const float* hp = P.hbuf + b * NN * DD + c;
      float q0 = 0.f, q1 = 0.f, q2 = 0.f, q3 = 0.f;
#pragma unroll 4
      for (int j4 = 0; j4 < NN / 4; ++j4) {
        float4 av = ar4[j4];
        const float* hj = hp + j4 * 4 * DD;
        q0 += av.x * hj[0];
        q1 += av.y * hj[DD];
        q2 += av.z * hj[2 * DD];
        q3 += av.w * hj[3 * DD];
      }
      float hpr = fmaxf((q0 + q1) + (q2 + q3), 0.f);
      float xr = cur[r * DD + c];
      float v = xr * gW[c] + hpr * gW[DD + c];
#pragma unroll
      for (int off = 32; off > 0; off >>= 1) v += __shfl_down(v, off);
      if ((tid & 63) == 0) redw[g][(tid >> 6) & 1] = v;
      __syncthreads();
      float coeff = sigmoidf_(redw[g][0] + redw[g][1] + gb[0]);
      nxt[r * DD + c] = coeff * xr + (1.f - coeff) * hpr;
    }
    { float* t = cur; cur = nxt; nxt = t; }
    grid.sync();
  }
  // cur == final ligand features h1gF

  // ================= Phase P: pair projections. 6 rows/block. =============
  // blocks 0..127 ligand -> p1 (+bias); 128..255 protein -> p2q packed.
  {
    bool lig = blk < 128;
    int rbase = lig ? blk * 6 : blk * 6 - 768;
    const float* src = lig ? cur : P.h2g;
    const float* xbase = src + rbase * DD;   // block-uniform -> s_loads
    for (int pass = 0; pass < 2; ++pass) {
      int o = tid + pass * 384;
      if (o < 640) {
        int m = o >> 7, hc = o & 127;
        const float* Wcol = P.pW1 + (m * 256 + (lig ? 0 : 128)) * HH + hc;
        float acc[6] = {0.f, 0.f, 0.f, 0.f, 0.f, 0.f};
#pragma unroll 4
        for (int k = 0; k < DD; ++k) {
          float w = Wcol[k * HH];
#pragma unroll
          for (int r = 0; r < 6; ++r) acc[r] += xbase[r * DD + k] * w;
        }
        if (lig) {
          float bias = P.pb1[m * HH + hc];
#pragma unroll
          for (int r = 0; r < 6; ++r)
            P.p1[((rbase + r) * 5 + m) * HH + hc] = acc[r] + bias;
        } else {
          float* dst = P.p2q + (size_t)((m * 32 + (hc >> 2)) * 768 + rbase) * 4 + (hc & 3);
#pragma unroll
          for (int r = 0; r < 6; ++r) dst[4 * r] = acc[r];
        }
      }
    }
  }
  grid.sync();

  // ================= Phase E2: pair energies (3 rows/block, lane=j) ========
  {
    int b = blk >> 7;
    int r0 = blk * 3;
    int j = tid;
    int col = b * NN + j;
    const float* q0 = P.p1 + (r0 + 0) * 640;   // uniform -> s_load
    const float* q1 = P.p1 + (r0 + 1) * 640;
    const float* q2 = P.p1 + (r0 + 2) * 640;
    const float4* p2q4 = (const float4*)P.p2q;
    float am[3][5];
#pragma unroll
    for (int m = 0; m < 5; ++m) {
      const float4* pc = p2q4 + (size_t)(m * 32) * 768 + col;
      const float* w2m = P.pW2 + m * HH;
      const float* x0 = q0 + m * HH;
      const float* x1 = q1 + m * HH;
      const float* x2 = q2 + m * HH;
      float a0 = 0.f, a1 = 0.f, a2 = 0.f;
#pragma unroll 4
      for (int hq = 0; hq < 32; ++hq) {
        float4 pv = pc[(size_t)hq * 768];
        float w0 = w2m[4 * hq], w1 = w2m[4 * hq + 1], w2v = w2m[4 * hq + 2], w3 = w2m[4 * hq + 3];
        a0 += fmaxf(x0[4 * hq] + pv.x, 0.f) * w0 + fmaxf(x0[4 * hq + 1] + pv.y, 0.f) * w1
            + fmaxf(x0[4 * hq + 2] + pv.z, 0.f) * w2v + fmaxf(x0[4 * hq + 3] + pv.w, 0.f) * w3;
        a1 += fmaxf(x1[4 * hq] + pv.x, 0.f) * w0 + fmaxf(x1[4 * hq + 1] + pv.y, 0.f) * w1
            + fmaxf(x1[4 * hq + 2] + pv.z, 0.f) * w2v + fmaxf(x1[4 * hq + 3] + pv.w, 0.f) * w3;
        a2 += fmaxf(x2[4 * hq] + pv.x, 0.f) * w0 + fmaxf(x2[4 * hq + 1] + pv.y, 0.f) * w1
            + fmaxf(x2[4 * hq + 2] + pv.z, 0.f) * w2v + fmaxf(x2[4 * hq + 3] + pv.w, 0.f) * w3;
      }
      float bb = P.pb2[m];
      am[0][m] = a0 + bb; am[1][m] = a1 + bb; am[2][m] = a2 + bb;
    }

    float q2c = P.charge2[col], vv2 = P.valid2[col], n2 = P.nm2[col];
    float vc2 = P.vdw_coeff[0] * P.vdw_coeff[0];
    float ec_sum = 0.f, ev_sum = 0.f;
#pragma unroll
    for (int ti = 0; ti < 3; ++ti) {
      int gi = r0 + ti;
      int pidx = gi * NN + j;
      float dx = P.dmv[pidx * 3], dy = P.dmv[pidx * 3 + 1], dz = P.dmv[pidx * 3 + 2];
      float dm = sqrtf(dx * dx + dy * dy + dz * dz + 1e-10f);
      if (dm < 0.5f) dm = 1e10f;
      float cA = sigmoidf_(am[ti][0]);
      float cN = sigmoidf_(am[ti][1]) * 2.f + 1.f;
      float e_c = cA * P.charge1[gi] * q2c * __powf(1.f / dm, cN);
      e_c *= P.valid1[gi] * vv2;
      e_c = fminf(fmaxf(e_c, -100.f), 100.f);
      ec_sum += e_c;
      float vA = (sigmoidf_(am[ti][2]) * 0.6f + 0.7f) * vc2 * P.veps[pidx];
      float vB = tanhf_(am[ti][3]) * 0.6f + 0.7f;
      float vN = sigmoidf_(am[ti][4]) * 2.f + 5.f;
      float dm0 = P.vsig[pidx] * vB;
      if (dm0 < 1e-4f) dm0 = 1.f;
      float rr = __powf(dm0 / dm, vN);
      float e_v = vA * (rr * rr - 2.f * rr);
      e_v *= P.nm1[gi] * n2;
      e_v = fminf(e_v, 100.f);
      ev_sum += e_v;
    }
#pragma unroll
    for (int off = 32; off > 0; off >>= 1) {
      ec_sum += __shfl_down(ec_sum, off);
      ev_sum += __shfl_down(ev_sum, off);
    }
    __shared__ float rec[6], rev[6];
    if ((tid & 63) == 0) { rec[tid >> 6] = ec_sum; rev[tid >> 6] = ev_sum; }
    __syncthreads();
    if (tid == 0) {
      float a = 0.f, cc = 0.f;
#pragma unroll
      for (int w = 0; w < 6; ++w) { a += rec[w]; cc += rev[w]; }
      atomicAdd(&P.out[b * 4 + 0], a);
      atomicAdd(&P.out[b * 4 + 1], cc);
    }
    // intercept partial row-sums (8 blocks)
    if (blk < 8 && tid < DD) {
      int bb = blk >> 2, ch = blk & 3;
      float acc = 0.f;
      int i0 = ch * 96;
#pragma unroll 4
      for (int i = 0; i < 96; ++i) {
        int gi = bb * NN + i0 + i;
        acc += cur[gi * DD + tid] * P.valid1[gi];
      }
      P.ws_int[blk * DD + tid] = acc;
    }
  }
  grid.sync();

  // ================= FIN: intercept MLP (block 0) ==========================
  if (blk == 0) {
    __shared__ float hsf[2][DD];
    __shared__ float redf[2][2];
    int bb = tid >> 7;
    int cc2 = tid & 127;
    if (bb < 2) {
      hsf[bb][cc2] = P.ws_int[(bb * 4 + 0) * DD + cc2] + P.ws_int[(bb * 4 + 1) * DD + cc2]
                   + P.ws_int[(bb * 4 + 2) * DD + cc2] + P.ws_int[(bb * 4 + 3) * DD + cc2];
    }
    __syncthreads();
    if (bb < 2) {
      float hid = P.ib1[cc2];
#pragma unroll 4
      for (int k = 0; k < DD; ++k) hid += hsf[bb][k] * P.iW1[k * HH + cc2];
      hid = fmaxf(hid, 0.f);
      float v = hid * P.iW2[cc2];
#pragma unroll
      for (int off = 32; off > 0; off >>= 1) v += __shfl_down(v, off);
      if ((tid & 63) == 0) redf[bb][(tid >> 6) & 1] = v;
    }
    __syncthreads();
    if (tid < 2) P.out[tid * 4 + 3] = redf[tid][0] + redf[tid][1] + P.ib2[0];
  }
}

// ---------------------------------------------------------------- launch
extern "C" void kernel_launch(void* const* d_in, const int* in_sizes, int n_in,
                              void* d_out, int out_size, void* d_ws, size_t ws_size,
                              hipStream_t stream) {
  (void)in_sizes; (void)n_in; (void)out_size; (void)ws_size;
  Params P;
  P.h1         = (const float*)d_in[0];
  P.h2         = (const float*)d_in[1];
  P.adj1       = (const float*)d_in[2];
  P.dmv        = (const float*)d_in[3];
  P.charge1    = (const float*)d_in[4];
  P.charge2    = (const float*)d_in[5];
  P.veps       = (const float*)d_in[6];
  P.vsig       = (const float*)d_in[7];
  P.delta_uff  = (const float*)d_in[8];
  P.valid1     = (const float*)d_in[9];
  P.valid2     = (const float*)d_in[10];
  P.nm1        = (const float*)d_in[11];
  P.nm2        = (const float*)d_in[12];
  P.node_W     = (const float*)d_in[13];
  P.gat_W      = (const float*)d_in[14];
  P.gat_Wb     = (const float*)d_in[15];
  P.gat_A      = (const float*)d_in[16];
  P.gat_gW     = (const float*)d_in[17];
  P.gat_gb     = (const float*)d_in[18];
  P.pW1        = (const float*)d_in[19];
  P.pb1        = (const float*)d_in[20];
  P.pW2        = (const float*)d_in[21];
  P.pb2        = (const float*)d_in[22];
  P.vdw_coeff  = (const float*)d_in[23];
  P.duff_coeff = (const float*)d_in[24];
  P.iW1        = (const float*)d_in[25];
  P.ib1        = (const float*)d_in[26];
  P.iW2        = (const float*)d_in[27];
  P.ib2        = (const float*)d_in[28];
  P.out = (float*)d_out;

  float* ws = (float*)d_ws;
  const int RN = 768 * DD;  // 98304
  P.h1gA   = ws;
  P.h1gB   = P.h1gA + RN;
  P.h2g    = P.h1gB + RN;
  P.hbuf   = P.h2g + RN;
  P.hAbuf  = P.hbuf + RN;
  P.hTbuf  = P.hAbuf + RN;
  P.hATbuf = P.hTbuf + RN;
  P.att    = P.hATbuf + RN;          // 2*384*384
  P.p1     = P.att + 2 * NN * NN;    // 768*640
  P.p2q    = P.p1 + 768 * 640;       // 768*640 packed float4
  P.ws_int = P.p2q + 768 * 640;      // 8*128

  void* args[] = { &P };
  hipLaunchCooperativeKernel((const void*)k_mega, dim3(256), dim3(384), args, 0, stream);
}

// Round 8
// 309.124 us; speedup vs baseline: 2.4621x; 2.4621x over previous
//
#include <hip/hip_runtime.h>
#include <math.h>

#define NN 384
#define DD 128
#define HH 128

__device__ __forceinline__ float sigmoidf_(float x) { return 1.f / (1.f + __expf(-x)); }
__device__ __forceinline__ float tanhf_(float x)    { return 1.f - 2.f / (__expf(2.f * x) + 1.f); }

// ================= k_start: embed + hhA(0) (ligand) / embed + proj (protein)
// 256 blocks x 384 thr. Blocks 0..127: 6 ligand rows. 128..255: 6 protein rows.
__global__ __launch_bounds__(384) void k_start(
    const float* __restrict__ h1, const float* __restrict__ h2,
    const float* __restrict__ nW,
    const float* __restrict__ W, const float* __restrict__ Wb, const float* __restrict__ A,
    const float* __restrict__ pW1,
    const float* __restrict__ delta_uff, const float* __restrict__ duff,
    float* __restrict__ h1g, float* __restrict__ h2g,
    float* __restrict__ hb, float* __restrict__ hAb,
    float* __restrict__ hT, float* __restrict__ hAT,
    float* __restrict__ p2q, float* __restrict__ out) {
  int blk = blockIdx.x, tid = threadIdx.x, c = tid & 127, g = tid >> 7;
  if (blk == 0 && tid < 8) {
    int bb = tid >> 2, cc = tid & 3;
    out[tid] = (cc == 2) ? duff[0] * duff[0] * delta_uff[bb] : 0.f;
  }
  if (blk < 128) {
    int rb = blk * 6;
    __shared__ float hs[6][DD];
#pragma unroll
    for (int p = 0; p < 2; ++p) {          // embed 6 rows
      int r = rb + p * 3 + g;
      const float* xr = h1 + r * 54;
      float acc = 0.f;
#pragma unroll 6
      for (int k = 0; k < 54; ++k) acc += xr[k] * nW[k * DD + c];
      h1g[r * DD + c] = acc;
    }
    __syncthreads();
#pragma unroll
    for (int p = 0; p < 2; ++p) {          // h = x@W + Wb
      int r = rb + p * 3 + g;
      const float4* xr4 = (const float4*)(h1g + r * DD);
      float a0 = 0.f, a1 = 0.f;
#pragma unroll 4
      for (int k4 = 0; k4 < DD / 4; ++k4) {
        float4 xv = xr4[k4]; int k = 4 * k4;
        a0 += xv.x * W[k * DD + c] + xv.z * W[(k + 2) * DD + c];
        a1 += xv.y * W[(k + 1) * DD + c] + xv.w * W[(k + 3) * DD + c];
      }
      float hv = a0 + a1 + Wb[c];
      hb[r * DD + c] = hv; hT[c * 768 + r] = hv; hs[p * 3 + g][c] = hv;
    }
    __syncthreads();
#pragma unroll
    for (int p = 0; p < 2; ++p) {          // hA = h@A
      int r = rb + p * 3 + g;
      const float4* hs4 = (const float4*)hs[p * 3 + g];
      float a0 = 0.f, a1 = 0.f;
#pragma unroll 4
      for (int k4 = 0; k4 < DD / 4; ++k4) {
        float4 xv = hs4[k4]; int k = 4 * k4;
        a0 += xv.x * A[k * DD + c] + xv.z * A[(k + 2) * DD + c];
        a1 += xv.y * A[(k + 1) * DD + c] + xv.w * A[(k + 3) * DD + c];
      }
      float av = a0 + a1;
      hAb[r * DD + c] = av; hAT[c * 768 + r] = av;
    }
  } else {
    int rb = (blk - 128) * 6;
#pragma unroll
    for (int p = 0; p < 2; ++p) {          // embed 6 protein rows
      int r = rb + p * 3 + g;
      const float* xr = h2 + r * 54;
      float acc = 0.f;
#pragma unroll 6
      for (int k = 0; k < 54; ++k) acc += xr[k] * nW[k * DD + c];
      h2g[r * DD + c] = acc;
    }
    __syncthreads();
    const float* xbase = h2g + rb * DD;    // block-uniform -> s_loads
    for (int pass = 0; pass < 2; ++pass) { // protein projection -> p2q packed
      int o = tid + pass * 384;
      if (o < 640) {
        int m = o >> 7, hc = o & 127;
        const float* Wcol = pW1 + (m * 256 + 128) * HH + hc;
        float acc[6] = {0.f, 0.f, 0.f, 0.f, 0.f, 0.f};
#pragma unroll 4
        for (int k = 0; k < DD; ++k) {
          float w = Wcol[k * HH];
#pragma unroll
          for (int r = 0; r < 6; ++r) acc[r] += xbase[r * DD + k] * w;
        }
        float* dst = p2q + (size_t)((m * 32 + (hc >> 2)) * 768 + rb) * 4 + (hc & 3);
#pragma unroll
        for (int r = 0; r < 6; ++r) dst[4 * r] = acc[r];
      }
    }
  }
}

// ================= k_att: 3 softmax columns/block, 256 blocks x 384 thr ====
__global__ __launch_bounds__(384) void k_att(
    const float* __restrict__ hb, const float* __restrict__ hAb,
    const float* __restrict__ hT, const float* __restrict__ hAT,
    const float* __restrict__ adj, float* __restrict__ att) {
  int blk = blockIdx.x, tid = threadIdx.x;
  __shared__ float red[3][6];
  int b = blk >> 7;
  int k0g = blk * 3;
  int kk0 = k0g - b * NN;
  int j = tid;
  const float* hTb  = hT  + b * NN + j;
  const float* hATb = hAT + b * NN + j;
  const float* h0r = hb  + (k0g + 0) * DD;
  const float* h1r = hb  + (k0g + 1) * DD;
  const float* h2r = hb  + (k0g + 2) * DD;
  const float* a0r = hAb + (k0g + 0) * DD;
  const float* a1r = hAb + (k0g + 1) * DD;
  const float* a2r = hAb + (k0g + 2) * DD;
  float e0 = 0.f, e1 = 0.f, e2 = 0.f;
#pragma unroll 4
  for (int cc = 0; cc < DD; ++cc) {
    float tv = hTb[cc * 768], av = hATb[cc * 768];
    e0 += av * h0r[cc] + tv * a0r[cc];
    e1 += av * h1r[cc] + tv * a1r[cc];
    e2 += av * h2r[cc] + tv * a2r[cc];
  }
  float aj0 = adj[(k0g + 0) * NN + j];   // adj symmetric
  float aj1 = adj[(k0g + 1) * NN + j];
  float aj2 = adj[(k0g + 2) * NN + j];
  float l0 = aj0 > 0.f ? e0 : -3e38f;
  float l1 = aj1 > 0.f ? e1 : -3e38f;
  float l2 = aj2 > 0.f ? e2 : -3e38f;
#pragma unroll
  for (int off = 32; off > 0; off >>= 1) {
    l0 = fmaxf(l0, __shfl_down(l0, off));
    l1 = fmaxf(l1, __shfl_down(l1, off));
    l2 = fmaxf(l2, __shfl_down(l2, off));
  }
  int w = tid >> 6;
  if ((tid & 63) == 0) { red[0][w] = l0; red[1][w] = l1; red[2][w] = l2; }
  __syncthreads();
  float m0 = red[0][0], m1 = red[1][0], m2 = red[2][0];
#pragma unroll
  for (int q = 1; q < 6; ++q) {
    m0 = fmaxf(m0, red[0][q]); m1 = fmaxf(m1, red[1][q]); m2 = fmaxf(m2, red[2][q]);
  }
  float v0 = aj0 > 0.f ? __expf(e0 - m0) : 0.f;
  float v1 = aj1 > 0.f ? __expf(e1 - m1) : 0.f;
  float v2 = aj2 > 0.f ? __expf(e2 - m2) : 0.f;
  float s0 = v0, s1 = v1, s2 = v2;
#pragma unroll
  for (int off = 32; off > 0; off >>= 1) {
    s0 += __shfl_down(s0, off);
    s1 += __shfl_down(s1, off);
    s2 += __shfl_down(s2, off);
  }
  __syncthreads();
  if ((tid & 63) == 0) { red[0][w] = s0; red[1][w] = s1; red[2][w] = s2; }
  __syncthreads();
  float d0 = 0.f, d1 = 0.f, d2 = 0.f;
#pragma unroll
  for (int q = 0; q < 6; ++q) { d0 += red[0][q]; d1 += red[1][q]; d2 += red[2][q]; }
  float* arow = att + (b * NN + j) * NN + kk0;
  arow[0] = v0 * aj0 / d0;
  arow[1] = v1 * aj1 / d1;
  arow[2] = v2 * aj2 / d2;
}

// ================= k_out_hhA: gated output(l) + hhA(l+1), row-local fuse ===
__global__ __launch_bounds__(384) void k_out_hhA(
    const float* __restrict__ x, const float* __restrict__ hb,
    const float* __restrict__ att,
    const float* __restrict__ gW, const float* __restrict__ gb,
    const float* __restrict__ Wn, const float* __restrict__ Wbn,
    const float* __restrict__ An,
    float* __restrict__ xout,
    float* __restrict__ hbn, float* __restrict__ hAbn,
    float* __restrict__ hTn, float* __restrict__ hATn) {
  int blk = blockIdx.x, tid = threadIdx.x, c = tid & 127, g = tid >> 7;
  __shared__ float redw[3][2];
  __shared__ float hsx[3][DD];
  __shared__ float hsh[3][DD];
  int r = blk * 3 + g, b = blk >> 7;
  // ---- gated output
  const float4* ar4 = (const float4*)(att + r * NN);
  const float* hp = hb + b * NN * DD + c;
  float q0 = 0.f, q1 = 0.f, q2 = 0.f, q3 = 0.f;
#pragma unroll 4
  for (int j4 = 0; j4 < NN / 4; ++j4) {
    float4 av = ar4[j4];
    const float* hj = hp + j4 * 4 * DD;
    q0 += av.x * hj[0];
    q1 += av.y * hj[DD];
    q2 += av.z * hj[2 * DD];
    q3 += av.w * hj[3 * DD];
  }
  float hpr = fmaxf((q0 + q1) + (q2 + q3), 0.f);
  float xr = x[r * DD + c];
  float v = xr * gW[c] + hpr * gW[DD + c];
#pragma unroll
  for (int off = 32; off > 0; off >>= 1) v += __shfl_down(v, off);
  if ((tid & 63) == 0) redw[g][(tid >> 6) & 1] = v;
  __syncthreads();
  float coeff = sigmoidf_(redw[g][0] + redw[g][1] + gb[0]);
  float nv = coeff * xr + (1.f - coeff) * hpr;
  xout[r * DD + c] = nv;
  hsx[g][c] = nv;
  __syncthreads();
  // ---- hhA next layer on the same row
  const float4* xs4 = (const float4*)hsx[g];
  float a0 = 0.f, a1 = 0.f;
#pragma unroll 4
  for (int k4 = 0; k4 < DD / 4; ++k4) {
    float4 xv = xs4[k4]; int k = 4 * k4;
    a0 += xv.x * Wn[k * DD + c] + xv.z * Wn[(k + 2) * DD + c];
    a1 += xv.y * Wn[(k + 1) * DD + c] + xv.w * Wn[(k + 3) * DD + c];
  }
  float hv = a0 + a1 + Wbn[c];
  hbn[r * DD + c] = hv; hTn[c * 768 + r] = hv;
  hsh[g][c] = hv;
  __syncthreads();
  const float4* hs4 = (const float4*)hsh[g];
  a0 = 0.f; a1 = 0.f;
#pragma unroll 4
  for (int k4 = 0; k4 < DD / 4; ++k4) {
    float4 xv = hs4[k4]; int k = 4 * k4;
    a0 += xv.x * An[k * DD + c] + xv.z * An[(k + 2) * DD + c];
    a1 += xv.y * An[(k + 1) * DD + c] + xv.w * An[(k + 3) * DD + c];
  }
  float av2 = a0 + a1;
  hAbn[r * DD + c] = av2; hATn[c * 768 + r] = av2;
}

// ================= k_out_proj: output(2) + ligand proj + intercept partials
__global__ __launch_bounds__(384) void k_out_proj(
    const float* __restrict__ x, const float* __restrict__ hb,
    const float* __restrict__ att,
    const float* __restrict__ gW, const float* __restrict__ gb,
    const float* __restrict__ pW1, const float* __restrict__ pb1,
    const float* __restrict__ valid1,
    float* __restrict__ xout, float* __restrict__ p1, float* __restrict__ ws_int) {
  int blk = blockIdx.x, tid = threadIdx.x, c = tid & 127, g = tid >> 7;
  __shared__ float redw[3][2];
  __shared__ float po[3][DD];
  int r = blk * 3 + g, b = blk >> 7;
  const float4* ar4 = (const float4*)(att + r * NN);
  const float* hp = hb + b * NN * DD + c;
  float q0 = 0.f, q1 = 0.f, q2 = 0.f, q3 = 0.f;
#pragma unroll 4
  for (int j4 = 0; j4 < NN / 4; ++j4) {
    float4 av = ar4[j4];
    const float* hj = hp + j4 * 4 * DD;
    q0 += av.x * hj[0];
    q1 += av.y * hj[DD];
    q2 += av.z * hj[2 * DD];
    q3 += av.w * hj[3 * DD];
  }
  float hpr = fmaxf((q0 + q1) + (q2 + q3), 0.f);
  float xr = x[r * DD + c];
  float v = xr * gW[c] + hpr * gW[DD + c];
#pragma unroll
  for (int off = 32; off > 0; off >>= 1) v += __shfl_down(v, off);
  if ((tid & 63) == 0) redw[g][(tid >> 6) & 1] = v;
  __syncthreads();
  float coeff = sigmoidf_(redw[g][0] + redw[g][1] + gb[0]);
  float nv = coeff * xr + (1.f - coeff) * hpr;
  xout[r * DD + c] = nv;
  po[g][c] = nv * valid1[r];
  __syncthreads();
  if (g == 0) ws_int[blk * DD + c] = po[0][c] + po[1][c] + po[2][c];
  // ---- ligand projection for the 3 rows (x rows via uniform s_loads)
  const float* xbase = xout + blk * 3 * DD;
  int rb = blk * 3;
  for (int pass = 0; pass < 2; ++pass) {
    int o = tid + pass * 384;
    if (o < 640) {
      int m = o >> 7, hc = o & 127;
      const float* Wcol = pW1 + (m * 256) * HH + hc;
      float acc[3] = {0.f, 0.f, 0.f};
#pragma unroll 4
      for (int k = 0; k < DD; ++k) {
        float w = Wcol[k * HH];
#pragma unroll
        for (int rr = 0; rr < 3; ++rr) acc[rr] += xbase[rr * DD + k] * w;
      }
      float bias = pb1[m * HH + hc];
#pragma unroll
      for (int rr = 0; rr < 3; ++rr)
        p1[((rb + rr) * 5 + m) * HH + hc] = acc[rr] + bias;
    }
  }
}

// ================= k_energy: 3 ligand rows/block, lane = j =================
__global__ __launch_bounds__(384) void k_energy(
    const float* __restrict__ p1, const float* __restrict__ p2q,
    const float* __restrict__ W2, const float* __restrict__ b2,
    const float* __restrict__ dmv, const float* __restrict__ charge1,
    const float* __restrict__ charge2, const float* __restrict__ veps,
    const float* __restrict__ vsig, const float* __restrict__ valid1,
    const float* __restrict__ valid2, const float* __restrict__ nm1,
    const float* __restrict__ nm2, const float* __restrict__ vdw_coeff,
    float* __restrict__ out) {
  int blk = blockIdx.x, tid = threadIdx.x;
  int b = blk >> 7;
  int r0 = blk * 3;
  int j = tid;
  int col = b * NN + j;
  const float* q0 = p1 + (r0 + 0) * 640;   // uniform -> s_load
  const float* q1 = p1 + (r0 + 1) * 640;
  const float* q2 = p1 + (r0 + 2) * 640;
  const float4* p2q4 = (const float4*)p2q;
  float am[3][5];
#pragma unroll
  for (int m = 0; m < 5; ++m) {
    const float4* pc = p2q4 + (size_t)(m * 32) * 768 + col;
    const float* w2m = W2 + m * HH;
    const float* x0 = q0 + m * HH;
    const float* x1 = q1 + m * HH;
    const float* x2 = q2 + m * HH;
    float a0 = 0.f, a1 = 0.f, a2 = 0.f;
#pragma unroll 4
    for (int hq = 0; hq < 32; ++hq) {
      float4 pv = pc[(size_t)hq * 768];
      float w0 = w2m[4 * hq], w1 = w2m[4 * hq + 1], w2v = w2m[4 * hq + 2], w3 = w2m[4 * hq + 3];
      a0 += fmaxf(x0[4 * hq] + pv.x, 0.f) * w0 + fmaxf(x0[4 * hq + 1] + pv.y, 0.f) * w1
          + fmaxf(x0[4 * hq + 2] + pv.z, 0.f) * w2v + fmaxf(x0[4 * hq + 3] + pv.w, 0.f) * w3;
      a1 += fmaxf(x1[4 * hq] + pv.x, 0.f) * w0 + fmaxf(x1[4 * hq + 1] + pv.y, 0.f) * w1
          + fmaxf(x1[4 * hq + 2] + pv.z, 0.f) * w2v + fmaxf(x1[4 * hq + 3] + pv.w, 0.f) * w3;
      a2 += fmaxf(x2[4 * hq] + pv.x, 0.f) * w0 + fmaxf(x2[4 * hq + 1] + pv.y, 0.f) * w1
          + fmaxf(x2[4 * hq + 2] + pv.z, 0.f) * w2v + fmaxf(x2[4 * hq + 3] + pv.w, 0.f) * w3;
    }
    float bb = b2[m];
    am[0][m] = a0 + bb; am[1][m] = a1 + bb; am[2][m] = a2 + bb;
  }

  float q2c = charge2[col], vv2 = valid2[col], n2 = nm2[col];
  float vc2 = vdw_coeff[0] * vdw_coeff[0];
  float ec_sum = 0.f, ev_sum = 0.f;
#pragma unroll
  for (int ti = 0; ti < 3; ++ti) {
    int gi = r0 + ti;
    int pidx = gi * NN + j;
    float dx = dmv[pidx * 3], dy = dmv[pidx * 3 + 1], dz = dmv[pidx * 3 + 2];
    float dm = sqrtf(dx * dx + dy * dy + dz * dz + 1e-10f);
    if (dm < 0.5f) dm = 1e10f;
    float cA = sigmoidf_(am[ti][0]);
    float cN = sigmoidf_(am[ti][1]) * 2.f + 1.f;
    float e_c = cA * charge1[gi] * q2c * __powf(1.f / dm, cN);
    e_c *= valid1[gi] * vv2;
    e_c = fminf(fmaxf(e_c, -100.f), 100.f);
    ec_sum += e_c;
    float vA = (sigmoidf_(am[ti][2]) * 0.6f + 0.7f) * vc2 * veps[pidx];
    float vB = tanhf_(am[ti][3]) * 0.6f + 0.7f;
    float vN = sigmoidf_(am[ti][4]) * 2.f + 5.f;
    float dm0 = vsig[pidx] * vB;
    if (dm0 < 1e-4f) dm0 = 1.f;
    float rr = __powf(dm0 / dm, vN);
    float e_v = vA * (rr * rr - 2.f * rr);
    e_v *= nm1[gi] * n2;
    e_v = fminf(e_v, 100.f);
    ev_sum += e_v;
  }
#pragma unroll
  for (int off = 32; off > 0; off >>= 1) {
    ec_sum += __shfl_down(ec_sum, off);
    ev_sum += __shfl_down(ev_sum, off);
  }
  __shared__ float rec[6], rev[6];
  if ((tid & 63) == 0) { rec[tid >> 6] = ec_sum; rev[tid >> 6] = ev_sum; }
  __syncthreads();
  if (tid == 0) {
    float a = 0.f, cc = 0.f;
#pragma unroll
    for (int w = 0; w < 6; ++w) { a += rec[w]; cc += rev[w]; }
    atomicAdd(&out[b * 4 + 0], a);
    atomicAdd(&out[b * 4 + 1], cc);
  }
}

// ================= k_fin: intercept MLP ====================================
__global__ __launch_bounds__(256) void k_fin(
    const float* __restrict__ ws_int, const float* __restrict__ iW1,
    const float* __restrict__ ib1, const float* __restrict__ iW2,
    const float* __restrict__ ib2, float* __restrict__ out) {
  int tid = threadIdx.x, bb = tid >> 7, cc = tid & 127;
  __shared__ float hsf[2][DD];
  __shared__ float redf[2][2];
  float acc = 0.f;
  for (int q = 0; q < 128; ++q) acc += ws_int[(bb * 128 + q) * DD + cc];
  hsf[bb][cc] = acc;
  __syncthreads();
  float hid = ib1[cc];
#pragma unroll 4
  for (int k = 0; k < DD; ++k) hid += hsf[bb][k] * iW1[k * HH + cc];
  hid = fmaxf(hid, 0.f);
  float v = hid * iW2[cc];
#pragma unroll
  for (int off = 32; off > 0; off >>= 1) v += __shfl_down(v, off);
  if ((tid & 63) == 0) redf[bb][(tid >> 6) & 1] = v;
  __syncthreads();
  if (tid < 2) out[tid * 4 + 3] = redf[tid][0] + redf[tid][1] + ib2[0];
}

// ---------------------------------------------------------------- launch
extern "C" void kernel_launch(void* const* d_in, const int* in_sizes, int n_in,
                              void* d_out, int out_size, void* d_ws, size_t ws_size,
                              hipStream_t stream) {
  (void)in_sizes; (void)n_in; (void)out_size; (void)ws_size;
  const float* h1         = (const float*)d_in[0];
  const float* h2         = (const float*)d_in[1];
  const float* adj1       = (const float*)d_in[2];
  const float* dmv        = (const float*)d_in[3];
  const float* charge1    = (const float*)d_in[4];
  const float* charge2    = (const float*)d_in[5];
  const float* veps       = (const float*)d_in[6];
  const float* vsig       = (const float*)d_in[7];
  const float* delta_uff  = (const float*)d_in[8];
  const float* valid1     = (const float*)d_in[9];
  const float* valid2     = (const float*)d_in[10];
  const float* nm1        = (const float*)d_in[11];
  const float* nm2        = (const float*)d_in[12];
  const float* node_W     = (const float*)d_in[13];
  const float* gat_W      = (const float*)d_in[14];
  const float* gat_Wb     = (const float*)d_in[15];
  const float* gat_A      = (const float*)d_in[16];
  const float* gat_gW     = (const float*)d_in[17];
  const float* gat_gb     = (const float*)d_in[18];
  const float* pW1        = (const float*)d_in[19];
  const float* pb1        = (const float*)d_in[20];
  const float* pW2        = (const float*)d_in[21];
  const float* pb2        = (const float*)d_in[22];
  const float* vdw_coeff  = (const float*)d_in[23];
  const float* duff_coeff = (const float*)d_in[24];
  const float* iW1        = (const float*)d_in[25];
  const float* ib1        = (const float*)d_in[26];
  const float* iW2        = (const float*)d_in[27];
  const float* ib2        = (const float*)d_in[28];
  float* out = (float*)d_out;

  float* ws = (float*)d_ws;
  const int RN = 768 * DD;  // 98304
  float* h1gA = ws;               // layer ping-pong A
  float* h1gB = h1gA + RN;        // layer ping-pong B (also final)
  float* h2g  = h1gB + RN;
  float* hb0  = h2g  + RN;
  float* hA0  = hb0  + RN;
  float* hT0  = hA0  + RN;
  float* hAT0 = hT0  + RN;
  float* hb1  = hAT0 + RN;
  float* hA1  = hb1  + RN;
  float* hT1  = hA1  + RN;
  float* hAT1 = hT1  + RN;
  float* att  = hAT1 + RN;            // 2*384*384
  float* p1   = att + 2 * NN * NN;    // 768*640
  float* p2q  = p1 + 768 * 640;       // 768*640 packed
  float* wsi  = p2q + 768 * 640;      // 256*128

  const int DD2 = DD * DD;

  // embed + hhA(0) + protein proj
  k_start<<<dim3(256), dim3(384), 0, stream>>>(
      h1, h2, node_W, gat_W, gat_Wb, gat_A, pW1, delta_uff, duff_coeff,
      h1gA, h2g, hb0, hA0, hT0, hAT0, p2q, out);

  // layer 0
  k_att<<<dim3(256), dim3(384), 0, stream>>>(hb0, hA0, hT0, hAT0, adj1, att);
  k_out_hhA<<<dim3(256), dim3(384), 0, stream>>>(
      h1gA, hb0, att, gat_gW + 0, gat_gb + 0,
      gat_W + DD2, gat_Wb + DD, gat_A + DD2,
      h1gB, hb1, hA1, hT1, hAT1);
  // layer 1
  k_att<<<dim3(256), dim3(384), 0, stream>>>(hb1, hA1, hT1, hAT1, adj1, att);
  k_out_hhA<<<dim3(256), dim3(384), 0, stream>>>(
      h1gB, hb1, att, gat_gW + 2 * DD, gat_gb + 1,
      gat_W + 2 * DD2, gat_Wb + 2 * DD, gat_A + 2 * DD2,
      h1gA, hb0, hA0, hT0, hAT0);
  // layer 2
  k_att<<<dim3(256), dim3(384), 0, stream>>>(hb0, hA0, hT0, hAT0, adj1, att);
  k_out_proj<<<dim3(256), dim3(384), 0, stream>>>(
      h1gA, hb0, att, gat_gW + 4 * DD, gat_gb + 2,
      pW1, pb1, valid1, h1gB, p1, wsi);

  k_energy<<<dim3(256), dim3(384), 0, stream>>>(
      p1, p2q, pW2, pb2, dmv, charge1, charge2, veps, vsig,
      valid1, valid2, nm1, nm2, vdw_coeff, out);
  k_fin<<<dim3(1), dim3(256), 0, stream>>>(wsi, iW1, ib1, iW2, ib2, out);
}